// Round 1
// baseline (171.560 us; speedup 1.0000x reference)
//
#include <hip/hip_runtime.h>
#include <math.h>

// ---------------------------------------------------------------------------
// OBB CIoU loss, N independent box pairs -> scalar mean.
// Per-thread: rotated-rect intersection area via the reference's
// "24 candidate vertices, sort by angle around centroid, shoelace" algorithm,
// then CIoU terms, then block reduction + atomicAdd of blocksum/N.
// Sort is a Batcher odd-even mergesort network generated at compile time so
// all array indexing is static (registers, no scratch).
// ---------------------------------------------------------------------------

#define BLOCK 256

// --- compile-time Batcher odd-even mergesort network for n=24 (padded to 32,
//     compare-exchanges touching indices >=24 dropped: virtual +inf tail) ---
struct CEList {
    int n;
    unsigned char lo[256];
    unsigned char hi[256];
};

constexpr CEList make_ces() {
    CEList L{};
    L.n = 0;
    for (int p = 1; p < 32; p <<= 1)
        for (int k = p; k >= 1; k >>= 1)
            for (int j = k % p; j + k < 32; j += 2 * k)
                for (int i = 0; i < k; i++) {
                    int lo = i + j, hi = i + j + k;
                    if (hi < 24 && (lo / (2 * p)) == (hi / (2 * p))) {
                        L.lo[L.n] = (unsigned char)lo;
                        L.hi[L.n] = (unsigned char)hi;
                        L.n++;
                    }
                }
    return L;
}

constexpr CEList CES = make_ces();

__global__ __launch_bounds__(BLOCK)
void obb_ciou_kernel(const float* __restrict__ pred,
                     const float* __restrict__ tgt,
                     const float* __restrict__ wgt,
                     float* __restrict__ out,
                     int N, float invN)
{
    const float EPSf  = 1e-8f;   // segment-intersection eps (reference EPS)
    const float TOLf  = 1e-6f;   // box_in_box tol
    const float MEPS  = 1e-6f;   // MODE_EPS
    const float PIf   = 3.14159265358979323846f;

    int i = blockIdx.x * blockDim.x + threadIdx.x;
    float loss = 0.f;

    if (i < N) {
        const float* p = pred + (size_t)i * 5;
        const float* t = tgt  + (size_t)i * 5;
        float pcx = p[0], pcy = p[1], pw = p[2], ph = p[3], pa = p[4];
        float tcx = t[0], tcy = t[1], tw = t[2], th = t[3], ta = t[4];

        // ---- corners ----
        float c1x[4], c1y[4], c2x[4], c2y[4];
        {
            const float xs[4] = { 0.5f, -0.5f, -0.5f, 0.5f };
            const float ys[4] = { -0.5f, -0.5f, 0.5f, 0.5f };
            float ca = cosf(pa), sa = sinf(pa);
            float cb = cosf(ta), sb = sinf(ta);
            #pragma unroll
            for (int k = 0; k < 4; k++) {
                float x4 = xs[k] * pw, y4 = ys[k] * ph;
                c1x[k] = x4 * ca - y4 * sa + pcx;
                c1y[k] = x4 * sa + y4 * ca + pcy;
                float x4b = xs[k] * tw, y4b = ys[k] * th;
                c2x[k] = x4b * cb - y4b * sb + tcx;
                c2y[k] = x4b * sb + y4b * cb + tcy;
            }
        }

        // ---- 24 candidate vertices + validity masks ----
        float vx[24], vy[24];
        bool  msk[24];

        // corners1 inside box2  (verts 0..3)
        {
            float ax = c2x[0], ay = c2y[0];
            float abx = c2x[1] - ax, aby = c2y[1] - ay;
            float adx = c2x[3] - ax, ady = c2y[3] - ay;
            float abab = abx * abx + aby * aby;
            float adad = adx * adx + ady * ady;
            #pragma unroll
            for (int k = 0; k < 4; k++) {
                float amx = c1x[k] - ax, amy = c1y[k] - ay;
                float pab = (abx * amx + aby * amy) / abab;
                float pad = (adx * amx + ady * amy) / adad;
                msk[k] = (pab > -TOLf) && (pab < 1.f + TOLf) &&
                         (pad > -TOLf) && (pad < 1.f + TOLf);
                vx[k] = c1x[k]; vy[k] = c1y[k];
            }
        }
        // corners2 inside box1  (verts 4..7)
        {
            float ax = c1x[0], ay = c1y[0];
            float abx = c1x[1] - ax, aby = c1y[1] - ay;
            float adx = c1x[3] - ax, ady = c1y[3] - ay;
            float abab = abx * abx + aby * aby;
            float adad = adx * adx + ady * ady;
            #pragma unroll
            for (int k = 0; k < 4; k++) {
                float amx = c2x[k] - ax, amy = c2y[k] - ay;
                float pab = (abx * amx + aby * amy) / abab;
                float pad = (adx * amx + ady * amy) / adad;
                msk[4 + k] = (pab > -TOLf) && (pab < 1.f + TOLf) &&
                             (pad > -TOLf) && (pad < 1.f + TOLf);
                vx[4 + k] = c2x[k]; vy[4 + k] = c2y[k];
            }
        }
        // edge x edge intersections (verts 8..23, index 8 + e1*4 + e2)
        #pragma unroll
        for (int e1 = 0; e1 < 4; e1++) {
            float x1 = c1x[e1], y1 = c1y[e1];
            float x2 = c1x[(e1 + 1) & 3], y2 = c1y[(e1 + 1) & 3];
            #pragma unroll
            for (int e2 = 0; e2 < 4; e2++) {
                float x3 = c2x[e2], y3 = c2y[e2];
                float x4 = c2x[(e2 + 1) & 3], y4 = c2y[(e2 + 1) & 3];
                float num   = (y4 - y3) * (x2 - x1) - (x4 - x3) * (y2 - y1);
                float den_t = (x4 - x3) * (y1 - y3) - (y4 - y3) * (x1 - x3);
                float tt = den_t / (num + EPSf);
                float den_u = (x2 - x1) * (y1 - y3) - (y2 - y1) * (x1 - x3);
                float uu = -den_u / (num + EPSf);
                bool m = (num != 0.f) && (tt > 0.f) && (tt < 1.f)
                                      && (uu > 0.f) && (uu < 1.f);
                float px = x1 + tt * (x2 - x1);
                float py = y1 + tt * (y2 - y1);
                int idx = 8 + e1 * 4 + e2;
                vx[idx] = m ? px : 0.f;
                vy[idx] = m ? py : 0.f;
                msk[idx] = m;
            }
        }

        // ---- centroid of valid verts ----
        float sx = 0.f, sy = 0.f, cnt = 0.f;
        #pragma unroll
        for (int k = 0; k < 24; k++) {
            sx  += msk[k] ? vx[k] : 0.f;
            sy  += msk[k] ? vy[k] : 0.f;
            cnt += msk[k] ? 1.f : 0.f;
        }
        float denom = fmaxf(cnt, 1.f);
        float cxc = sx / denom, cyc = sy / denom;

        // ---- relative coords + angle key (invalid -> 1e7, sorts to end) ----
        float ang[24];
        #pragma unroll
        for (int k = 0; k < 24; k++) {
            vx[k] -= cxc;
            vy[k] -= cyc;
            ang[k] = msk[k] ? atan2f(vy[k], vx[k]) : 1e7f;
        }

        // ---- sort 24 triples by angle (Batcher network, static indices) ----
        #pragma unroll
        for (int c = 0; c < CES.n; c++) {
            const int lo = CES.lo[c], hi = CES.hi[c];
            float a0 = ang[lo], a1 = ang[hi];
            bool sw = a0 > a1;
            ang[lo] = sw ? a1 : a0;  ang[hi] = sw ? a0 : a1;
            float x0 = vx[lo], x1v = vx[hi];
            vx[lo] = sw ? x1v : x0;  vx[hi] = sw ? x0 : x1v;
            float y0 = vy[lo], y1v = vy[hi];
            vy[lo] = sw ? y1v : y0;  vy[hi] = sw ? y0 : y1v;
        }

        // ---- shoelace over sorted polygon; invalid slots -> first vertex ----
        float fx = vx[0], fy = vy[0];
        float cross = 0.f;
        #pragma unroll
        for (int k = 0; k < 24; k++) {
            int kn = (k + 1) % 24;          // constant after unroll
            bool mk = ang[k]  < 1e6f;        // valid angles <= pi << 1e6
            bool mn = ang[kn] < 1e6f;
            float axv = mk ? vx[k]  : fx, ayv = mk ? vy[k]  : fy;
            float bxv = mn ? vx[kn] : fx, byv = mn ? vy[kn] : fy;
            cross += axv * byv - ayv * bxv;
        }
        float inter = fabsf(cross) * 0.5f;

        // ---- CIoU ----
        float area1 = pw * ph, area2 = tw * th;
        float iou = inter / (area1 + area2 - inter);
        iou = fminf(fmaxf(iou, 0.f), 1.f);

        float cA = fabsf(cosf(pa)), sA = fabsf(sinf(pa));
        float cB = fabsf(cosf(ta)), sB = fabsf(sinf(ta));
        float dw1 = (pw * cA + ph * sA) * 0.5f, dh1 = (pw * sA + ph * cA) * 0.5f;
        float dw2 = (tw * cB + th * sB) * 0.5f, dh2 = (tw * sB + th * cB) * 0.5f;
        float hp0 = pcx - dw1, hp1 = pcy - dh1, hp2 = pcx + dw1, hp3 = pcy + dh1;
        float ht0 = tcx - dw2, ht1 = tcy - dh2, ht2 = tcx + dw2, ht3 = tcy + dh2;

        float enw = fmaxf(fmaxf(hp2, ht2) - fminf(hp0, ht0), 0.f);
        float enh = fmaxf(fmaxf(hp3, ht3) - fminf(hp1, ht1), 0.f);
        float c2v = enw * enw + enh * enh + MEPS;
        float rho2 = (tcx - pcx) * (tcx - pcx) + (tcy - pcy) * (tcy - pcy);

        float factor = 4.f / (PIf * PIf);
        float dv = atanf(tw / (th + MEPS)) - atanf(pw / (ph + MEPS));
        float v_ = factor * dv * dv;
        float alpha = (iou > 0.5f) ? v_ / (1.f - iou + v_ + MEPS) : 0.f;

        float rhoterm = fminf(fmaxf(rho2 / c2v, 0.f), 1.f);
        float ciou = iou - (rhoterm + alpha * v_);
        loss = (1.f - ciou) * wgt[i];
    }

    // ---- reduction: wave shuffle -> LDS -> one atomic per block ----
    #pragma unroll
    for (int off = 32; off > 0; off >>= 1)
        loss += __shfl_down(loss, off, 64);

    __shared__ float red[BLOCK / 64];
    int wave = threadIdx.x >> 6;
    int lane = threadIdx.x & 63;
    if (lane == 0) red[wave] = loss;
    __syncthreads();
    if (threadIdx.x == 0) {
        float s = 0.f;
        #pragma unroll
        for (int w = 0; w < BLOCK / 64; w++) s += red[w];
        atomicAdd(out, s * invN);
    }
}

extern "C" void kernel_launch(void* const* d_in, const int* in_sizes, int n_in,
                              void* d_out, int out_size, void* d_ws, size_t ws_size,
                              hipStream_t stream) {
    const float* pred = (const float*)d_in[0];
    const float* tgt  = (const float*)d_in[1];
    const float* wgt  = (const float*)d_in[2];
    float* out = (float*)d_out;
    int N = in_sizes[2];  // weight element count == N boxes

    // d_out is re-poisoned to 0xAA before every launch; we accumulate into it.
    hipMemsetAsync(out, 0, sizeof(float) * (size_t)out_size, stream);

    int grid = (N + BLOCK - 1) / BLOCK;
    obb_ciou_kernel<<<grid, BLOCK, 0, stream>>>(pred, tgt, wgt, out, N,
                                                1.f / (float)N);
}

// Round 3
// 148.825 us; speedup vs baseline: 1.1528x; 1.1528x over previous
//
#include <hip/hip_runtime.h>
#include <math.h>

// ---------------------------------------------------------------------------
// OBB CIoU loss, N independent box pairs -> scalar mean.
// R3: exact-reference algorithm (R1 passed absmax 0.0) with VALU-count
// optimizations that preserve semantics up to measure-zero tie flips:
//   - atan2f replaced by a diamond pseudo-angle (monotone-equivalent key)
//   - precise divides replaced by v_rcp_f32 (~1 ulp) in intersection and
//     box-in-box tests
// R2 note: a Green's-theorem clipped-edge rewrite produced systematically
// inflated intersection areas (mean loss 0.945 -> ~0.39) despite the formula
// hand-verifying on 3 cases; shelved.
// ---------------------------------------------------------------------------

#define BLOCK 256

// --- compile-time Batcher odd-even mergesort network for n=24 (padded to 32,
//     compare-exchanges touching indices >=24 dropped: virtual +inf tail) ---
struct CEList {
    int n;
    unsigned char lo[256];
    unsigned char hi[256];
};

constexpr CEList make_ces() {
    CEList L{};
    L.n = 0;
    for (int p = 1; p < 32; p <<= 1)
        for (int k = p; k >= 1; k >>= 1)
            for (int j = k % p; j + k < 32; j += 2 * k)
                for (int i = 0; i < k; i++) {
                    int lo = i + j, hi = i + j + k;
                    if (hi < 24 && (lo / (2 * p)) == (hi / (2 * p))) {
                        L.lo[L.n] = (unsigned char)lo;
                        L.hi[L.n] = (unsigned char)hi;
                        L.n++;
                    }
                }
    return L;
}

constexpr CEList CES = make_ces();

__device__ __forceinline__ float frcp(float x) {
    return __builtin_amdgcn_rcpf(x);
}

// Diamond pseudo-angle: strictly increasing function of atan2(y,x) on
// (-pi, pi], range (2, 6].  atan2=-pi+ -> 2+, -pi/2 -> 3, 0 -> 4,
// +pi/2 -> 5, +pi -> 6.  Order-equivalent to sorting by atan2.
__device__ __forceinline__ float angle_key(float x, float y) {
    float ax = fabsf(x), ay = fabsf(y);
    float den = ax + ay;
    float r = x * frcp(den);
    r = (den > 0.f) ? r : 0.f;               // (0,0): atan2=0 -> key 4
    float d4 = (y >= 0.f) ? (1.f - r) : (3.f + r);
    return (d4 > 2.f) ? d4 : d4 + 4.f;
}

__global__ __launch_bounds__(BLOCK)
void obb_ciou_kernel(const float* __restrict__ pred,
                     const float* __restrict__ tgt,
                     const float* __restrict__ wgt,
                     float* __restrict__ out,
                     int N, float invN)
{
    const float EPSf  = 1e-8f;   // segment-intersection eps (reference EPS)
    const float TOLf  = 1e-6f;   // box_in_box tol
    const float MEPS  = 1e-6f;   // MODE_EPS
    const float PIf   = 3.14159265358979323846f;

    int i = blockIdx.x * blockDim.x + threadIdx.x;
    float loss = 0.f;

    if (i < N) {
        const float* p = pred + (size_t)i * 5;
        const float* t = tgt  + (size_t)i * 5;
        float pcx = p[0], pcy = p[1], pw = p[2], ph = p[3], pa = p[4];
        float tcx = t[0], tcy = t[1], tw = t[2], th = t[3], ta = t[4];
        float wv  = wgt[i];

        // ---- corners ----
        float c1x[4], c1y[4], c2x[4], c2y[4];
        {
            const float xs[4] = { 0.5f, -0.5f, -0.5f, 0.5f };
            const float ys[4] = { -0.5f, -0.5f, 0.5f, 0.5f };
            float ca = cosf(pa), sa = sinf(pa);
            float cb = cosf(ta), sb = sinf(ta);
            #pragma unroll
            for (int k = 0; k < 4; k++) {
                float x4 = xs[k] * pw, y4 = ys[k] * ph;
                c1x[k] = x4 * ca - y4 * sa + pcx;
                c1y[k] = x4 * sa + y4 * ca + pcy;
                float x4b = xs[k] * tw, y4b = ys[k] * th;
                c2x[k] = x4b * cb - y4b * sb + tcx;
                c2y[k] = x4b * sb + y4b * cb + tcy;
            }
        }

        // ---- 24 candidate vertices + validity masks ----
        float vx[24], vy[24];
        bool  msk[24];

        // corners1 inside box2  (verts 0..3)
        {
            float ax = c2x[0], ay = c2y[0];
            float abx = c2x[1] - ax, aby = c2y[1] - ay;
            float adx = c2x[3] - ax, ady = c2y[3] - ay;
            float rab = frcp(abx * abx + aby * aby);
            float rad = frcp(adx * adx + ady * ady);
            #pragma unroll
            for (int k = 0; k < 4; k++) {
                float amx = c1x[k] - ax, amy = c1y[k] - ay;
                float pab = (abx * amx + aby * amy) * rab;
                float pad = (adx * amx + ady * amy) * rad;
                msk[k] = (pab > -TOLf) && (pab < 1.f + TOLf) &&
                         (pad > -TOLf) && (pad < 1.f + TOLf);
                vx[k] = c1x[k]; vy[k] = c1y[k];
            }
        }
        // corners2 inside box1  (verts 4..7)
        {
            float ax = c1x[0], ay = c1y[0];
            float abx = c1x[1] - ax, aby = c1y[1] - ay;
            float adx = c1x[3] - ax, ady = c1y[3] - ay;
            float rab = frcp(abx * abx + aby * aby);
            float rad = frcp(adx * adx + ady * ady);
            #pragma unroll
            for (int k = 0; k < 4; k++) {
                float amx = c2x[k] - ax, amy = c2y[k] - ay;
                float pab = (abx * amx + aby * amy) * rab;
                float pad = (adx * amx + ady * amy) * rad;
                msk[4 + k] = (pab > -TOLf) && (pab < 1.f + TOLf) &&
                             (pad > -TOLf) && (pad < 1.f + TOLf);
                vx[4 + k] = c2x[k]; vy[4 + k] = c2y[k];
            }
        }
        // edge x edge intersections (verts 8..23, index 8 + e1*4 + e2)
        #pragma unroll
        for (int e1 = 0; e1 < 4; e1++) {
            float x1 = c1x[e1], y1 = c1y[e1];
            float x2 = c1x[(e1 + 1) & 3], y2 = c1y[(e1 + 1) & 3];
            float ex = x2 - x1, ey = y2 - y1;
            #pragma unroll
            for (int e2 = 0; e2 < 4; e2++) {
                float x3 = c2x[e2], y3 = c2y[e2];
                float x4 = c2x[(e2 + 1) & 3], y4 = c2y[(e2 + 1) & 3];
                float fx = x4 - x3, fy = y4 - y3;
                float num   = fy * ex - fx * ey;
                float rnum  = frcp(num + EPSf);
                float den_t = fx * (y1 - y3) - fy * (x1 - x3);
                float tt = den_t * rnum;
                float den_u = ex * (y1 - y3) - ey * (x1 - x3);
                float uu = -den_u * rnum;
                bool m = (num != 0.f) && (tt > 0.f) && (tt < 1.f)
                                      && (uu > 0.f) && (uu < 1.f);
                int idx = 8 + e1 * 4 + e2;
                vx[idx] = m ? (x1 + tt * ex) : 0.f;
                vy[idx] = m ? (y1 + tt * ey) : 0.f;
                msk[idx] = m;
            }
        }

        // ---- centroid of valid verts ----
        float sx = 0.f, sy = 0.f, cnt = 0.f;
        #pragma unroll
        for (int k = 0; k < 24; k++) {
            sx  += msk[k] ? vx[k] : 0.f;
            sy  += msk[k] ? vy[k] : 0.f;
            cnt += msk[k] ? 1.f : 0.f;
        }
        float rden = frcp(fmaxf(cnt, 1.f));
        float cxc = sx * rden, cyc = sy * rden;

        // ---- relative coords + pseudo-angle key (invalid -> 1e7) ----
        float ang[24];
        #pragma unroll
        for (int k = 0; k < 24; k++) {
            vx[k] -= cxc;
            vy[k] -= cyc;
            ang[k] = msk[k] ? angle_key(vx[k], vy[k]) : 1e7f;
        }

        // ---- sort 24 triples by key (Batcher network, static indices) ----
        #pragma unroll
        for (int c = 0; c < CES.n; c++) {
            const int lo = CES.lo[c], hi = CES.hi[c];
            float a0 = ang[lo], a1 = ang[hi];
            bool sw = a0 > a1;
            ang[lo] = sw ? a1 : a0;  ang[hi] = sw ? a0 : a1;
            float x0 = vx[lo], x1v = vx[hi];
            vx[lo] = sw ? x1v : x0;  vx[hi] = sw ? x0 : x1v;
            float y0 = vy[lo], y1v = vy[hi];
            vy[lo] = sw ? y1v : y0;  vy[hi] = sw ? y0 : y1v;
        }

        // ---- shoelace over sorted polygon; invalid slots -> first vertex ----
        float fx = vx[0], fy = vy[0];
        float cross = 0.f;
        #pragma unroll
        for (int k = 0; k < 24; k++) {
            int kn = (k + 1) % 24;           // constant after unroll
            bool mk = ang[k]  < 1e6f;        // valid keys <= 6 << 1e6
            bool mn = ang[kn] < 1e6f;
            float axv = mk ? vx[k]  : fx, ayv = mk ? vy[k]  : fy;
            float bxv = mn ? vx[kn] : fx, byv = mn ? vy[kn] : fy;
            cross += axv * byv - ayv * bxv;
        }
        float inter = fabsf(cross) * 0.5f;

        // ---- CIoU ----
        float area1 = pw * ph, area2 = tw * th;
        float iou = inter / (area1 + area2 - inter);
        iou = fminf(fmaxf(iou, 0.f), 1.f);

        float ca = cosf(pa), sa = sinf(pa);
        float cb = cosf(ta), sb = sinf(ta);
        float cA = fabsf(ca), sA = fabsf(sa);
        float cB = fabsf(cb), sB = fabsf(sb);
        float dw1 = (pw * cA + ph * sA) * 0.5f, dh1 = (pw * sA + ph * cA) * 0.5f;
        float dw2 = (tw * cB + th * sB) * 0.5f, dh2 = (tw * sB + th * cB) * 0.5f;
        float hp0 = pcx - dw1, hp1 = pcy - dh1, hp2 = pcx + dw1, hp3 = pcy + dh1;
        float ht0 = tcx - dw2, ht1 = tcy - dh2, ht2 = tcx + dw2, ht3 = tcy + dh2;

        float enw = fmaxf(fmaxf(hp2, ht2) - fminf(hp0, ht0), 0.f);
        float enh = fmaxf(fmaxf(hp3, ht3) - fminf(hp1, ht1), 0.f);
        float c2v = enw * enw + enh * enh + MEPS;
        float rho2 = (tcx - pcx) * (tcx - pcx) + (tcy - pcy) * (tcy - pcy);

        float factor = 4.f / (PIf * PIf);
        float dv = atanf(tw / (th + MEPS)) - atanf(pw / (ph + MEPS));
        float v_ = factor * dv * dv;
        float alpha = (iou > 0.5f) ? v_ / (1.f - iou + v_ + MEPS) : 0.f;

        float rhoterm = fminf(fmaxf(rho2 / c2v, 0.f), 1.f);
        float ciou = iou - (rhoterm + alpha * v_);
        loss = (1.f - ciou) * wv;
    }

    // ---- reduction: wave shuffle -> LDS -> one atomic per block ----
    #pragma unroll
    for (int off = 32; off > 0; off >>= 1)
        loss += __shfl_down(loss, off, 64);

    __shared__ float red[BLOCK / 64];
    int wave = threadIdx.x >> 6;
    int lane = threadIdx.x & 63;
    if (lane == 0) red[wave] = loss;
    __syncthreads();
    if (threadIdx.x == 0) {
        float s = 0.f;
        #pragma unroll
        for (int w = 0; w < BLOCK / 64; w++) s += red[w];
        atomicAdd(out, s * invN);
    }
}

extern "C" void kernel_launch(void* const* d_in, const int* in_sizes, int n_in,
                              void* d_out, int out_size, void* d_ws, size_t ws_size,
                              hipStream_t stream) {
    const float* pred = (const float*)d_in[0];
    const float* tgt  = (const float*)d_in[1];
    const float* wgt  = (const float*)d_in[2];
    float* out = (float*)d_out;
    int N = in_sizes[2];  // weight element count == N boxes

    hipMemsetAsync(out, 0, sizeof(float) * (size_t)out_size, stream);

    int grid = (N + BLOCK - 1) / BLOCK;
    obb_ciou_kernel<<<grid, BLOCK, 0, stream>>>(pred, tgt, wgt, out, N,
                                                1.f / (float)N);
}

// Round 4
// 139.888 us; speedup vs baseline: 1.2264x; 1.0639x over previous
//
#include <hip/hip_runtime.h>
#include <math.h>

// ---------------------------------------------------------------------------
// OBB CIoU loss, N independent box pairs -> scalar mean.
// R4: shrink the angular sort from 24 -> 16 vertices. A segment crosses a
// convex quad's boundary at most twice, so each box1 edge contributes <=2
// valid intersections out of its 4 candidates; a static select-tree compacts
// them into 2 slots (same valid vertex set, no dynamic indexing). Sorted set:
// 8 corners + 8 compacted intersection slots. Batcher n=16 = 63 CEs (vs 131).
// Carried from R3: diamond pseudo-angle key (atan2-order-equivalent), v_rcp
// divides. R1 exact-reference semantics otherwise.
// ---------------------------------------------------------------------------

#define BLOCK 256
#define NV 16

// --- compile-time Batcher odd-even mergesort network for n=16 ---
struct CEList {
    int n;
    unsigned char lo[128];
    unsigned char hi[128];
};

constexpr CEList make_ces16() {
    CEList L{};
    L.n = 0;
    for (int p = 1; p < NV; p <<= 1)
        for (int k = p; k >= 1; k >>= 1)
            for (int j = k % p; j + k < NV; j += 2 * k)
                for (int i = 0; i < k; i++) {
                    int lo = i + j, hi = i + j + k;
                    if (hi < NV && (lo / (2 * p)) == (hi / (2 * p))) {
                        L.lo[L.n] = (unsigned char)lo;
                        L.hi[L.n] = (unsigned char)hi;
                        L.n++;
                    }
                }
    return L;
}

constexpr CEList CES = make_ces16();

__device__ __forceinline__ float frcp(float x) {
    return __builtin_amdgcn_rcpf(x);
}

// Diamond pseudo-angle: strictly increasing function of atan2(y,x) on
// (-pi, pi], range (2, 6]. Order-equivalent to sorting by atan2.
__device__ __forceinline__ float angle_key(float x, float y) {
    float ax = fabsf(x), ay = fabsf(y);
    float den = ax + ay;
    float r = x * frcp(den);
    r = (den > 0.f) ? r : 0.f;               // (0,0): atan2=0 -> key 4
    float d4 = (y >= 0.f) ? (1.f - r) : (3.f + r);
    return (d4 > 2.f) ? d4 : d4 + 4.f;
}

__global__ __launch_bounds__(BLOCK)
void obb_ciou_kernel(const float* __restrict__ pred,
                     const float* __restrict__ tgt,
                     const float* __restrict__ wgt,
                     float* __restrict__ out,
                     int N, float invN)
{
    const float EPSf  = 1e-8f;   // segment-intersection eps (reference EPS)
    const float TOLf  = 1e-6f;   // box_in_box tol
    const float MEPS  = 1e-6f;   // MODE_EPS
    const float PIf   = 3.14159265358979323846f;

    int i = blockIdx.x * blockDim.x + threadIdx.x;
    float loss = 0.f;

    if (i < N) {
        const float* p = pred + (size_t)i * 5;
        const float* t = tgt  + (size_t)i * 5;
        float pcx = p[0], pcy = p[1], pw = p[2], ph = p[3], pa = p[4];
        float tcx = t[0], tcy = t[1], tw = t[2], th = t[3], ta = t[4];
        float wv  = wgt[i];

        // ---- corners ----
        float c1x[4], c1y[4], c2x[4], c2y[4];
        float ca = cosf(pa), sa = sinf(pa);
        float cb = cosf(ta), sb = sinf(ta);
        {
            const float xs[4] = { 0.5f, -0.5f, -0.5f, 0.5f };
            const float ys[4] = { -0.5f, -0.5f, 0.5f, 0.5f };
            #pragma unroll
            for (int k = 0; k < 4; k++) {
                float x4 = xs[k] * pw, y4 = ys[k] * ph;
                c1x[k] = x4 * ca - y4 * sa + pcx;
                c1y[k] = x4 * sa + y4 * ca + pcy;
                float x4b = xs[k] * tw, y4b = ys[k] * th;
                c2x[k] = x4b * cb - y4b * sb + tcx;
                c2y[k] = x4b * sb + y4b * cb + tcy;
            }
        }

        // ---- 16 candidate vertices + validity masks ----
        float vx[NV], vy[NV];
        bool  msk[NV];

        // corners1 inside box2  (verts 0..3)
        {
            float ax = c2x[0], ay = c2y[0];
            float abx = c2x[1] - ax, aby = c2y[1] - ay;
            float adx = c2x[3] - ax, ady = c2y[3] - ay;
            float rab = frcp(abx * abx + aby * aby);
            float rad = frcp(adx * adx + ady * ady);
            #pragma unroll
            for (int k = 0; k < 4; k++) {
                float amx = c1x[k] - ax, amy = c1y[k] - ay;
                float pab = (abx * amx + aby * amy) * rab;
                float pad = (adx * amx + ady * amy) * rad;
                msk[k] = (pab > -TOLf) && (pab < 1.f + TOLf) &&
                         (pad > -TOLf) && (pad < 1.f + TOLf);
                vx[k] = c1x[k]; vy[k] = c1y[k];
            }
        }
        // corners2 inside box1  (verts 4..7)
        {
            float ax = c1x[0], ay = c1y[0];
            float abx = c1x[1] - ax, aby = c1y[1] - ay;
            float adx = c1x[3] - ax, ady = c1y[3] - ay;
            float rab = frcp(abx * abx + aby * aby);
            float rad = frcp(adx * adx + ady * ady);
            #pragma unroll
            for (int k = 0; k < 4; k++) {
                float amx = c2x[k] - ax, amy = c2y[k] - ay;
                float pab = (abx * amx + aby * amy) * rab;
                float pad = (adx * amx + ady * amy) * rad;
                msk[4 + k] = (pab > -TOLf) && (pab < 1.f + TOLf) &&
                             (pad > -TOLf) && (pad < 1.f + TOLf);
                vx[4 + k] = c2x[k]; vy[4 + k] = c2y[k];
            }
        }
        // edge x edge intersections, compacted 4 -> 2 per box1 edge
        // (verts 8..15, slots 8+2*e1 and 9+2*e1)
        #pragma unroll
        for (int e1 = 0; e1 < 4; e1++) {
            float x1 = c1x[e1], y1 = c1y[e1];
            float x2 = c1x[(e1 + 1) & 3], y2 = c1y[(e1 + 1) & 3];
            float ex = x2 - x1, ey = y2 - y1;
            float qx[4], qy[4];
            bool  qm[4];
            #pragma unroll
            for (int e2 = 0; e2 < 4; e2++) {
                float x3 = c2x[e2], y3 = c2y[e2];
                float x4 = c2x[(e2 + 1) & 3], y4 = c2y[(e2 + 1) & 3];
                float fx = x4 - x3, fy = y4 - y3;
                float num   = fy * ex - fx * ey;
                float rnum  = frcp(num + EPSf);
                float den_t = fx * (y1 - y3) - fy * (x1 - x3);
                float tt = den_t * rnum;
                float den_u = ex * (y1 - y3) - ey * (x1 - x3);
                float uu = -den_u * rnum;
                qm[e2] = (num != 0.f) && (tt > 0.f) && (tt < 1.f)
                                      && (uu > 0.f) && (uu < 1.f);
                qx[e2] = x1 + tt * ex;
                qy[e2] = y1 + tt * ey;
            }
            // first/second-valid selection (pairwise merge, static indices)
            bool  mfL = qm[0] || qm[1];
            float fLx = qm[0] ? qx[0] : qx[1];
            float fLy = qm[0] ? qy[0] : qy[1];
            bool  msL = qm[0] && qm[1];
            bool  mfR = qm[2] || qm[3];
            float fRx = qm[2] ? qx[2] : qx[3];
            float fRy = qm[2] ? qy[2] : qy[3];
            bool  msR = qm[2] && qm[3];
            int s0 = 8 + 2 * e1, s1 = s0 + 1;
            vx[s0]  = mfL ? fLx : fRx;
            vy[s0]  = mfL ? fLy : fRy;
            msk[s0] = mfL || mfR;
            float tx = msL ? qx[1] : fRx;
            float ty = msL ? qy[1] : fRy;
            vx[s1]  = mfL ? tx : qx[3];
            vy[s1]  = mfL ? ty : qy[3];
            msk[s1] = msL || (mfL && mfR) || msR;
        }

        // ---- centroid of valid verts ----
        float sx = 0.f, sy = 0.f, cnt = 0.f;
        #pragma unroll
        for (int k = 0; k < NV; k++) {
            sx  += msk[k] ? vx[k] : 0.f;
            sy  += msk[k] ? vy[k] : 0.f;
            cnt += msk[k] ? 1.f : 0.f;
        }
        float rden = frcp(fmaxf(cnt, 1.f));
        float cxc = sx * rden, cyc = sy * rden;

        // ---- relative coords + pseudo-angle key (invalid -> 1e7) ----
        float ang[NV];
        #pragma unroll
        for (int k = 0; k < NV; k++) {
            vx[k] -= cxc;
            vy[k] -= cyc;
            ang[k] = msk[k] ? angle_key(vx[k], vy[k]) : 1e7f;
        }

        // ---- sort 16 triples by key (Batcher network, static indices) ----
        #pragma unroll
        for (int c = 0; c < CES.n; c++) {
            const int lo = CES.lo[c], hi = CES.hi[c];
            float a0 = ang[lo], a1 = ang[hi];
            bool sw = a0 > a1;
            ang[lo] = sw ? a1 : a0;  ang[hi] = sw ? a0 : a1;
            float x0 = vx[lo], x1v = vx[hi];
            vx[lo] = sw ? x1v : x0;  vx[hi] = sw ? x0 : x1v;
            float y0 = vy[lo], y1v = vy[hi];
            vy[lo] = sw ? y1v : y0;  vy[hi] = sw ? y0 : y1v;
        }

        // ---- shoelace over sorted polygon; invalid slots -> first vertex ----
        float fx = vx[0], fy = vy[0];
        float cross = 0.f;
        #pragma unroll
        for (int k = 0; k < NV; k++) {
            int kn = (k + 1) % NV;           // constant after unroll
            bool mk = ang[k]  < 1e6f;        // valid keys <= 6 << 1e6
            bool mn = ang[kn] < 1e6f;
            float axv = mk ? vx[k]  : fx, ayv = mk ? vy[k]  : fy;
            float bxv = mn ? vx[kn] : fx, byv = mn ? vy[kn] : fy;
            cross += axv * byv - ayv * bxv;
        }
        float inter = fabsf(cross) * 0.5f;

        // ---- CIoU ----
        float area1 = pw * ph, area2 = tw * th;
        float iou = inter / (area1 + area2 - inter);
        iou = fminf(fmaxf(iou, 0.f), 1.f);

        float cA = fabsf(ca), sA = fabsf(sa);
        float cB = fabsf(cb), sB = fabsf(sb);
        float dw1 = (pw * cA + ph * sA) * 0.5f, dh1 = (pw * sA + ph * cA) * 0.5f;
        float dw2 = (tw * cB + th * sB) * 0.5f, dh2 = (tw * sB + th * cB) * 0.5f;
        float hp0 = pcx - dw1, hp1 = pcy - dh1, hp2 = pcx + dw1, hp3 = pcy + dh1;
        float ht0 = tcx - dw2, ht1 = tcy - dh2, ht2 = tcx + dw2, ht3 = tcy + dh2;

        float enw = fmaxf(fmaxf(hp2, ht2) - fminf(hp0, ht0), 0.f);
        float enh = fmaxf(fmaxf(hp3, ht3) - fminf(hp1, ht1), 0.f);
        float c2v = enw * enw + enh * enh + MEPS;
        float rho2 = (tcx - pcx) * (tcx - pcx) + (tcy - pcy) * (tcy - pcy);

        float factor = 4.f / (PIf * PIf);
        float dv = atanf(tw / (th + MEPS)) - atanf(pw / (ph + MEPS));
        float v_ = factor * dv * dv;
        float alpha = (iou > 0.5f) ? v_ / (1.f - iou + v_ + MEPS) : 0.f;

        float rhoterm = fminf(fmaxf(rho2 / c2v, 0.f), 1.f);
        float ciou = iou - (rhoterm + alpha * v_);
        loss = (1.f - ciou) * wv;
    }

    // ---- reduction: wave shuffle -> LDS -> one atomic per block ----
    #pragma unroll
    for (int off = 32; off > 0; off >>= 1)
        loss += __shfl_down(loss, off, 64);

    __shared__ float red[BLOCK / 64];
    int wave = threadIdx.x >> 6;
    int lane = threadIdx.x & 63;
    if (lane == 0) red[wave] = loss;
    __syncthreads();
    if (threadIdx.x == 0) {
        float s = 0.f;
        #pragma unroll
        for (int w = 0; w < BLOCK / 64; w++) s += red[w];
        atomicAdd(out, s * invN);
    }
}

extern "C" void kernel_launch(void* const* d_in, const int* in_sizes, int n_in,
                              void* d_out, int out_size, void* d_ws, size_t ws_size,
                              hipStream_t stream) {
    const float* pred = (const float*)d_in[0];
    const float* tgt  = (const float*)d_in[1];
    const float* wgt  = (const float*)d_in[2];
    float* out = (float*)d_out;
    int N = in_sizes[2];  // weight element count == N boxes

    hipMemsetAsync(out, 0, sizeof(float) * (size_t)out_size, stream);

    int grid = (N + BLOCK - 1) / BLOCK;
    obb_ciou_kernel<<<grid, BLOCK, 0, stream>>>(pred, tgt, wgt, out, N,
                                                1.f / (float)N);
}

// Round 5
// 126.347 us; speedup vs baseline: 1.3578x; 1.1072x over previous
//
#include <hip/hip_runtime.h>
#include <math.h>

// ---------------------------------------------------------------------------
// OBB CIoU loss, N independent box pairs -> scalar mean.
// R5: the R4 kernel became dependency-latency-bound (VALUBusy 48%, occupancy
// ~3 waves/SIMD): one long serial chain per thread. Fix: 2 independent box
// pairs per thread (ILP interleaving converts stalls to issue), plus native
// __sinf/__cosf (angles bounded, no heavy range reduction needed).
// Carried: 16-vertex compacted candidate set + Batcher n=16 sort (R4),
// diamond pseudo-angle key + v_rcp divides (R3), exact-reference algorithm.
// ---------------------------------------------------------------------------

#define BLOCK 256
#define NV 16

// --- compile-time Batcher odd-even mergesort network for n=16 ---
struct CEList {
    int n;
    unsigned char lo[128];
    unsigned char hi[128];
};

constexpr CEList make_ces16() {
    CEList L{};
    L.n = 0;
    for (int p = 1; p < NV; p <<= 1)
        for (int k = p; k >= 1; k >>= 1)
            for (int j = k % p; j + k < NV; j += 2 * k)
                for (int i = 0; i < k; i++) {
                    int lo = i + j, hi = i + j + k;
                    if (hi < NV && (lo / (2 * p)) == (hi / (2 * p))) {
                        L.lo[L.n] = (unsigned char)lo;
                        L.hi[L.n] = (unsigned char)hi;
                        L.n++;
                    }
                }
    return L;
}

constexpr CEList CES = make_ces16();

__device__ __forceinline__ float frcp(float x) {
    return __builtin_amdgcn_rcpf(x);
}

// Diamond pseudo-angle: strictly increasing function of atan2(y,x) on
// (-pi, pi], range (2, 6]. Order-equivalent to sorting by atan2.
__device__ __forceinline__ float angle_key(float x, float y) {
    float ax = fabsf(x), ay = fabsf(y);
    float den = ax + ay;
    float r = x * frcp(den);
    r = (den > 0.f) ? r : 0.f;               // (0,0): atan2=0 -> key 4
    float d4 = (y >= 0.f) ? (1.f - r) : (3.f + r);
    return (d4 > 2.f) ? d4 : d4 + 4.f;
}

__device__ __forceinline__ float pair_loss(const float* __restrict__ p,
                                           const float* __restrict__ t,
                                           float wv)
{
    const float EPSf  = 1e-8f;   // segment-intersection eps (reference EPS)
    const float TOLf  = 1e-6f;   // box_in_box tol
    const float MEPS  = 1e-6f;   // MODE_EPS
    const float PIf   = 3.14159265358979323846f;

    float pcx = p[0], pcy = p[1], pw = p[2], ph = p[3], pa = p[4];
    float tcx = t[0], tcy = t[1], tw = t[2], th = t[3], ta = t[4];

    // ---- corners ----  (angles bounded: |pa|<pi/2, |ta|<pi/2+0.3 -> native
    // sin/cos are a few-ulp accurate without ocml's heavy range reduction)
    float c1x[4], c1y[4], c2x[4], c2y[4];
    float ca = __cosf(pa), sa = __sinf(pa);
    float cb = __cosf(ta), sb = __sinf(ta);
    {
        const float xs[4] = { 0.5f, -0.5f, -0.5f, 0.5f };
        const float ys[4] = { -0.5f, -0.5f, 0.5f, 0.5f };
        #pragma unroll
        for (int k = 0; k < 4; k++) {
            float x4 = xs[k] * pw, y4 = ys[k] * ph;
            c1x[k] = x4 * ca - y4 * sa + pcx;
            c1y[k] = x4 * sa + y4 * ca + pcy;
            float x4b = xs[k] * tw, y4b = ys[k] * th;
            c2x[k] = x4b * cb - y4b * sb + tcx;
            c2y[k] = x4b * sb + y4b * cb + tcy;
        }
    }

    // ---- 16 candidate vertices + validity masks ----
    float vx[NV], vy[NV];
    bool  msk[NV];

    // corners1 inside box2  (verts 0..3)
    {
        float ax = c2x[0], ay = c2y[0];
        float abx = c2x[1] - ax, aby = c2y[1] - ay;
        float adx = c2x[3] - ax, ady = c2y[3] - ay;
        float rab = frcp(abx * abx + aby * aby);
        float rad = frcp(adx * adx + ady * ady);
        #pragma unroll
        for (int k = 0; k < 4; k++) {
            float amx = c1x[k] - ax, amy = c1y[k] - ay;
            float pab = (abx * amx + aby * amy) * rab;
            float pad = (adx * amx + ady * amy) * rad;
            msk[k] = (pab > -TOLf) && (pab < 1.f + TOLf) &&
                     (pad > -TOLf) && (pad < 1.f + TOLf);
            vx[k] = c1x[k]; vy[k] = c1y[k];
        }
    }
    // corners2 inside box1  (verts 4..7)
    {
        float ax = c1x[0], ay = c1y[0];
        float abx = c1x[1] - ax, aby = c1y[1] - ay;
        float adx = c1x[3] - ax, ady = c1y[3] - ay;
        float rab = frcp(abx * abx + aby * aby);
        float rad = frcp(adx * adx + ady * ady);
        #pragma unroll
        for (int k = 0; k < 4; k++) {
            float amx = c2x[k] - ax, amy = c2y[k] - ay;
            float pab = (abx * amx + aby * amy) * rab;
            float pad = (adx * amx + ady * amy) * rad;
            msk[4 + k] = (pab > -TOLf) && (pab < 1.f + TOLf) &&
                         (pad > -TOLf) && (pad < 1.f + TOLf);
            vx[4 + k] = c2x[k]; vy[4 + k] = c2y[k];
        }
    }
    // edge x edge intersections, compacted 4 -> 2 per box1 edge
    #pragma unroll
    for (int e1 = 0; e1 < 4; e1++) {
        float x1 = c1x[e1], y1 = c1y[e1];
        float x2 = c1x[(e1 + 1) & 3], y2 = c1y[(e1 + 1) & 3];
        float ex = x2 - x1, ey = y2 - y1;
        float qx[4], qy[4];
        bool  qm[4];
        #pragma unroll
        for (int e2 = 0; e2 < 4; e2++) {
            float x3 = c2x[e2], y3 = c2y[e2];
            float x4 = c2x[(e2 + 1) & 3], y4 = c2y[(e2 + 1) & 3];
            float fx = x4 - x3, fy = y4 - y3;
            float num   = fy * ex - fx * ey;
            float rnum  = frcp(num + EPSf);
            float den_t = fx * (y1 - y3) - fy * (x1 - x3);
            float tt = den_t * rnum;
            float den_u = ex * (y1 - y3) - ey * (x1 - x3);
            float uu = -den_u * rnum;
            qm[e2] = (num != 0.f) && (tt > 0.f) && (tt < 1.f)
                                  && (uu > 0.f) && (uu < 1.f);
            qx[e2] = x1 + tt * ex;
            qy[e2] = y1 + tt * ey;
        }
        bool  mfL = qm[0] || qm[1];
        float fLx = qm[0] ? qx[0] : qx[1];
        float fLy = qm[0] ? qy[0] : qy[1];
        bool  msL = qm[0] && qm[1];
        bool  mfR = qm[2] || qm[3];
        float fRx = qm[2] ? qx[2] : qx[3];
        float fRy = qm[2] ? qy[2] : qy[3];
        bool  msR = qm[2] && qm[3];
        int s0 = 8 + 2 * e1, s1 = s0 + 1;
        vx[s0]  = mfL ? fLx : fRx;
        vy[s0]  = mfL ? fLy : fRy;
        msk[s0] = mfL || mfR;
        float tx = msL ? qx[1] : fRx;
        float ty = msL ? qy[1] : fRy;
        vx[s1]  = mfL ? tx : qx[3];
        vy[s1]  = mfL ? ty : qy[3];
        msk[s1] = msL || (mfL && mfR) || msR;
    }

    // ---- centroid of valid verts ----
    float sx = 0.f, sy = 0.f, cnt = 0.f;
    #pragma unroll
    for (int k = 0; k < NV; k++) {
        sx  += msk[k] ? vx[k] : 0.f;
        sy  += msk[k] ? vy[k] : 0.f;
        cnt += msk[k] ? 1.f : 0.f;
    }
    float rden = frcp(fmaxf(cnt, 1.f));
    float cxc = sx * rden, cyc = sy * rden;

    // ---- relative coords + pseudo-angle key (invalid -> 1e7) ----
    float ang[NV];
    #pragma unroll
    for (int k = 0; k < NV; k++) {
        vx[k] -= cxc;
        vy[k] -= cyc;
        ang[k] = msk[k] ? angle_key(vx[k], vy[k]) : 1e7f;
    }

    // ---- sort 16 triples by key (Batcher network, static indices) ----
    #pragma unroll
    for (int c = 0; c < CES.n; c++) {
        const int lo = CES.lo[c], hi = CES.hi[c];
        float a0 = ang[lo], a1 = ang[hi];
        bool sw = a0 > a1;
        ang[lo] = sw ? a1 : a0;  ang[hi] = sw ? a0 : a1;
        float x0 = vx[lo], x1v = vx[hi];
        vx[lo] = sw ? x1v : x0;  vx[hi] = sw ? x0 : x1v;
        float y0 = vy[lo], y1v = vy[hi];
        vy[lo] = sw ? y1v : y0;  vy[hi] = sw ? y0 : y1v;
    }

    // ---- shoelace over sorted polygon; invalid slots -> first vertex ----
    float fx = vx[0], fy = vy[0];
    float cross = 0.f;
    #pragma unroll
    for (int k = 0; k < NV; k++) {
        int kn = (k + 1) % NV;           // constant after unroll
        bool mk = ang[k]  < 1e6f;        // valid keys <= 6 << 1e6
        bool mn = ang[kn] < 1e6f;
        float axv = mk ? vx[k]  : fx, ayv = mk ? vy[k]  : fy;
        float bxv = mn ? vx[kn] : fx, byv = mn ? vy[kn] : fy;
        cross += axv * byv - ayv * bxv;
    }
    float inter = fabsf(cross) * 0.5f;

    // ---- CIoU ----
    float area1 = pw * ph, area2 = tw * th;
    float iou = inter / (area1 + area2 - inter);
    iou = fminf(fmaxf(iou, 0.f), 1.f);

    float cA = fabsf(ca), sA = fabsf(sa);
    float cB = fabsf(cb), sB = fabsf(sb);
    float dw1 = (pw * cA + ph * sA) * 0.5f, dh1 = (pw * sA + ph * cA) * 0.5f;
    float dw2 = (tw * cB + th * sB) * 0.5f, dh2 = (tw * sB + th * cB) * 0.5f;
    float hp0 = pcx - dw1, hp1 = pcy - dh1, hp2 = pcx + dw1, hp3 = pcy + dh1;
    float ht0 = tcx - dw2, ht1 = tcy - dh2, ht2 = tcx + dw2, ht3 = tcy + dh2;

    float enw = fmaxf(fmaxf(hp2, ht2) - fminf(hp0, ht0), 0.f);
    float enh = fmaxf(fmaxf(hp3, ht3) - fminf(hp1, ht1), 0.f);
    float c2v = enw * enw + enh * enh + MEPS;
    float rho2 = (tcx - pcx) * (tcx - pcx) + (tcy - pcy) * (tcy - pcy);

    float factor = 4.f / (PIf * PIf);
    float dv = atanf(tw / (th + MEPS)) - atanf(pw / (ph + MEPS));
    float v_ = factor * dv * dv;
    float alpha = (iou > 0.5f) ? v_ / (1.f - iou + v_ + MEPS) : 0.f;

    float rhoterm = fminf(fmaxf(rho2 / c2v, 0.f), 1.f);
    float ciou = iou - (rhoterm + alpha * v_);
    return (1.f - ciou) * wv;
}

__global__ __launch_bounds__(BLOCK)
void obb_ciou_kernel(const float* __restrict__ pred,
                     const float* __restrict__ tgt,
                     const float* __restrict__ wgt,
                     float* __restrict__ out,
                     int N, float invN)
{
    int base = (blockIdx.x * blockDim.x + threadIdx.x) * 2;
    float loss = 0.f;

    // Two independent pairs per thread: the scheduler interleaves the two
    // dependency chains, converting latency stalls into issue cycles.
    #pragma unroll
    for (int u = 0; u < 2; u++) {
        int i = base + u;
        if (i < N)
            loss += pair_loss(pred + (size_t)i * 5, tgt + (size_t)i * 5,
                              wgt[i]);
    }

    // ---- reduction: wave shuffle -> LDS -> one atomic per block ----
    #pragma unroll
    for (int off = 32; off > 0; off >>= 1)
        loss += __shfl_down(loss, off, 64);

    __shared__ float red[BLOCK / 64];
    int wave = threadIdx.x >> 6;
    int lane = threadIdx.x & 63;
    if (lane == 0) red[wave] = loss;
    __syncthreads();
    if (threadIdx.x == 0) {
        float s = 0.f;
        #pragma unroll
        for (int w = 0; w < BLOCK / 64; w++) s += red[w];
        atomicAdd(out, s * invN);
    }
}

extern "C" void kernel_launch(void* const* d_in, const int* in_sizes, int n_in,
                              void* d_out, int out_size, void* d_ws, size_t ws_size,
                              hipStream_t stream) {
    const float* pred = (const float*)d_in[0];
    const float* tgt  = (const float*)d_in[1];
    const float* wgt  = (const float*)d_in[2];
    float* out = (float*)d_out;
    int N = in_sizes[2];  // weight element count == N boxes

    hipMemsetAsync(out, 0, sizeof(float) * (size_t)out_size, stream);

    int grid = (N + BLOCK * 2 - 1) / (BLOCK * 2);
    obb_ciou_kernel<<<grid, BLOCK, 0, stream>>>(pred, tgt, wgt, out, N,
                                                1.f / (float)N);
}

// Round 6
// 110.505 us; speedup vs baseline: 1.5525x; 1.1434x over previous
//
#include <hip/hip_runtime.h>
#include <math.h>

// ---------------------------------------------------------------------------
// OBB CIoU loss, N independent box pairs -> scalar mean.
// R6: two changes on top of R5 (59.6 us dispatch, VALUBusy 60%):
//  (a) key-index sort: pack (angle_key_bits & ~0xF) | slot into a uint,
//      sort 16 uints on the Batcher network (2 VALU/CE vs 7), then gather
//      (x,y) payload via a per-thread LDS slab (stride 17*8B -> only free
//      2-way bank aliasing). Pseudo-angle loses its +4 wrap: the resulting
//      key is a cyclic shift of the atan2 order and cyclic shoelace is
//      shift-invariant.
//  (b) 4 pairs/thread (strided for coalescing): more ILP to fill the 40%
//      no-issue cycles; LDS slab reused serially across the 4 pairs.
// Carried: 16-vertex compacted candidate set (R4), v_rcp divides + native
// sin/cos (R3/R5), exact-reference algorithm semantics.
// ---------------------------------------------------------------------------

#define BLOCK 256
#define NV 16
#define PAIRS 4
#define LDS_STRIDE 17   // 16 float2 slots + 1 pad: banks = 2*(t+idx) mod 32

// --- compile-time Batcher odd-even mergesort network for n=16 ---
struct CEList {
    int n;
    unsigned char lo[128];
    unsigned char hi[128];
};

constexpr CEList make_ces16() {
    CEList L{};
    L.n = 0;
    for (int p = 1; p < NV; p <<= 1)
        for (int k = p; k >= 1; k >>= 1)
            for (int j = k % p; j + k < NV; j += 2 * k)
                for (int i = 0; i < k; i++) {
                    int lo = i + j, hi = i + j + k;
                    if (hi < NV && (lo / (2 * p)) == (hi / (2 * p))) {
                        L.lo[L.n] = (unsigned char)lo;
                        L.hi[L.n] = (unsigned char)hi;
                        L.n++;
                    }
                }
    return L;
}

constexpr CEList CES = make_ces16();

__device__ __forceinline__ float frcp(float x) {
    return __builtin_amdgcn_rcpf(x);
}

// Diamond pseudo-angle, no wrap: d4 in [0,4), a CYCLIC SHIFT of atan2 order
// (starts at angle 0 instead of -pi). Cyclic shoelace is shift-invariant.
// Invalid vertices get 1e7 (sorts last). All values nonneg -> uint-monotone.
__device__ __forceinline__ float angle_key(float x, float y) {
    float ax = fabsf(x), ay = fabsf(y);
    float den = ax + ay;
    float r = x * frcp(den);
    r = (den > 0.f) ? r : 0.f;
    return (y >= 0.f) ? (1.f - r) : (3.f + r);
}

__device__ __forceinline__ float pair_loss(const float* __restrict__ p,
                                           const float* __restrict__ t,
                                           float wv, float2* __restrict__ myb)
{
    const float EPSf  = 1e-8f;   // segment-intersection eps (reference EPS)
    const float TOLf  = 1e-6f;   // box_in_box tol
    const float MEPS  = 1e-6f;   // MODE_EPS
    const float PIf   = 3.14159265358979323846f;

    float pcx = p[0], pcy = p[1], pw = p[2], ph = p[3], pa = p[4];
    float tcx = t[0], tcy = t[1], tw = t[2], th = t[3], ta = t[4];

    // ---- corners ---- (|angles| <= pi/2+0.3: native sin/cos sufficient)
    float c1x[4], c1y[4], c2x[4], c2y[4];
    float ca = __cosf(pa), sa = __sinf(pa);
    float cb = __cosf(ta), sb = __sinf(ta);
    {
        const float xs[4] = { 0.5f, -0.5f, -0.5f, 0.5f };
        const float ys[4] = { -0.5f, -0.5f, 0.5f, 0.5f };
        #pragma unroll
        for (int k = 0; k < 4; k++) {
            float x4 = xs[k] * pw, y4 = ys[k] * ph;
            c1x[k] = x4 * ca - y4 * sa + pcx;
            c1y[k] = x4 * sa + y4 * ca + pcy;
            float x4b = xs[k] * tw, y4b = ys[k] * th;
            c2x[k] = x4b * cb - y4b * sb + tcx;
            c2y[k] = x4b * sb + y4b * cb + tcy;
        }
    }

    // ---- 16 candidate vertices + validity masks ----
    float vx[NV], vy[NV];
    bool  msk[NV];

    // corners1 inside box2  (verts 0..3)
    {
        float ax = c2x[0], ay = c2y[0];
        float abx = c2x[1] - ax, aby = c2y[1] - ay;
        float adx = c2x[3] - ax, ady = c2y[3] - ay;
        float rab = frcp(abx * abx + aby * aby);
        float rad = frcp(adx * adx + ady * ady);
        #pragma unroll
        for (int k = 0; k < 4; k++) {
            float amx = c1x[k] - ax, amy = c1y[k] - ay;
            float pab = (abx * amx + aby * amy) * rab;
            float pad = (adx * amx + ady * amy) * rad;
            msk[k] = (pab > -TOLf) && (pab < 1.f + TOLf) &&
                     (pad > -TOLf) && (pad < 1.f + TOLf);
            vx[k] = c1x[k]; vy[k] = c1y[k];
        }
    }
    // corners2 inside box1  (verts 4..7)
    {
        float ax = c1x[0], ay = c1y[0];
        float abx = c1x[1] - ax, aby = c1y[1] - ay;
        float adx = c1x[3] - ax, ady = c1y[3] - ay;
        float rab = frcp(abx * abx + aby * aby);
        float rad = frcp(adx * adx + ady * ady);
        #pragma unroll
        for (int k = 0; k < 4; k++) {
            float amx = c2x[k] - ax, amy = c2y[k] - ay;
            float pab = (abx * amx + aby * amy) * rab;
            float pad = (adx * amx + ady * amy) * rad;
            msk[4 + k] = (pab > -TOLf) && (pab < 1.f + TOLf) &&
                         (pad > -TOLf) && (pad < 1.f + TOLf);
            vx[4 + k] = c2x[k]; vy[4 + k] = c2y[k];
        }
    }
    // edge x edge intersections, compacted 4 -> 2 per box1 edge
    #pragma unroll
    for (int e1 = 0; e1 < 4; e1++) {
        float x1 = c1x[e1], y1 = c1y[e1];
        float x2 = c1x[(e1 + 1) & 3], y2 = c1y[(e1 + 1) & 3];
        float ex = x2 - x1, ey = y2 - y1;
        float qx[4], qy[4];
        bool  qm[4];
        #pragma unroll
        for (int e2 = 0; e2 < 4; e2++) {
            float x3 = c2x[e2], y3 = c2y[e2];
            float x4 = c2x[(e2 + 1) & 3], y4 = c2y[(e2 + 1) & 3];
            float fx = x4 - x3, fy = y4 - y3;
            float num   = fy * ex - fx * ey;
            float rnum  = frcp(num + EPSf);
            float den_t = fx * (y1 - y3) - fy * (x1 - x3);
            float tt = den_t * rnum;
            float den_u = ex * (y1 - y3) - ey * (x1 - x3);
            float uu = -den_u * rnum;
            qm[e2] = (num != 0.f) && (tt > 0.f) && (tt < 1.f)
                                  && (uu > 0.f) && (uu < 1.f);
            qx[e2] = x1 + tt * ex;
            qy[e2] = y1 + tt * ey;
        }
        bool  mfL = qm[0] || qm[1];
        float fLx = qm[0] ? qx[0] : qx[1];
        float fLy = qm[0] ? qy[0] : qy[1];
        bool  msL = qm[0] && qm[1];
        bool  mfR = qm[2] || qm[3];
        float fRx = qm[2] ? qx[2] : qx[3];
        float fRy = qm[2] ? qy[2] : qy[3];
        bool  msR = qm[2] && qm[3];
        int s0 = 8 + 2 * e1, s1 = s0 + 1;
        vx[s0]  = mfL ? fLx : fRx;
        vy[s0]  = mfL ? fLy : fRy;
        msk[s0] = mfL || mfR;
        float tx = msL ? qx[1] : fRx;
        float ty = msL ? qy[1] : fRy;
        vx[s1]  = mfL ? tx : qx[3];
        vy[s1]  = mfL ? ty : qy[3];
        msk[s1] = msL || (mfL && mfR) || msR;
    }

    // ---- centroid of valid verts ----
    float sx = 0.f, sy = 0.f, cnt = 0.f;
    #pragma unroll
    for (int k = 0; k < NV; k++) {
        sx  += msk[k] ? vx[k] : 0.f;
        sy  += msk[k] ? vy[k] : 0.f;
        cnt += msk[k] ? 1.f : 0.f;
    }
    float rden = frcp(fmaxf(cnt, 1.f));
    float cxc = sx * rden, cyc = sy * rden;

    // ---- relative coords -> LDS scatter + packed key (key|slot) ----
    unsigned int ku[NV];
    #pragma unroll
    for (int k = 0; k < NV; k++) {
        float rx = vx[k] - cxc, ry = vy[k] - cyc;
        myb[k] = make_float2(rx, ry);
        float a = msk[k] ? angle_key(rx, ry) : 1e7f;
        ku[k] = (__float_as_uint(a) & 0xFFFFFFF0u) | (unsigned int)k;
    }

    // ---- sort 16 packed keys (Batcher network, 2 VALU per CE) ----
    #pragma unroll
    for (int c = 0; c < CES.n; c++) {
        const int lo = CES.lo[c], hi = CES.hi[c];
        unsigned int a = ku[lo], b = ku[hi];
        ku[lo] = a < b ? a : b;
        ku[hi] = a < b ? b : a;
    }

    // ---- gather payload by sorted index; shoelace ----
    const unsigned int VALID_LIM = 0x49742400u;  // bits of 1e6f
    float gx[NV], gy[NV];
    bool  gv[NV];
    #pragma unroll
    for (int k = 0; k < NV; k++) {
        float2 v = myb[ku[k] & 15u];
        gx[k] = v.x; gy[k] = v.y;
        gv[k] = ku[k] < VALID_LIM;
    }
    float fx = gx[0], fy = gy[0];
    float cross = 0.f;
    #pragma unroll
    for (int k = 0; k < NV; k++) {
        int kn = (k + 1) % NV;           // constant after unroll
        float axv = gv[k]  ? gx[k]  : fx, ayv = gv[k]  ? gy[k]  : fy;
        float bxv = gv[kn] ? gx[kn] : fx, byv = gv[kn] ? gy[kn] : fy;
        cross += axv * byv - ayv * bxv;
    }
    float inter = fabsf(cross) * 0.5f;

    // ---- CIoU ----
    float area1 = pw * ph, area2 = tw * th;
    float iou = inter / (area1 + area2 - inter);
    iou = fminf(fmaxf(iou, 0.f), 1.f);

    float cA = fabsf(ca), sA = fabsf(sa);
    float cB = fabsf(cb), sB = fabsf(sb);
    float dw1 = (pw * cA + ph * sA) * 0.5f, dh1 = (pw * sA + ph * cA) * 0.5f;
    float dw2 = (tw * cB + th * sB) * 0.5f, dh2 = (tw * sB + th * cB) * 0.5f;
    float hp0 = pcx - dw1, hp1 = pcy - dh1, hp2 = pcx + dw1, hp3 = pcy + dh1;
    float ht0 = tcx - dw2, ht1 = tcy - dh2, ht2 = tcx + dw2, ht3 = tcy + dh2;

    float enw = fmaxf(fmaxf(hp2, ht2) - fminf(hp0, ht0), 0.f);
    float enh = fmaxf(fmaxf(hp3, ht3) - fminf(hp1, ht1), 0.f);
    float c2v = enw * enw + enh * enh + MEPS;
    float rho2 = (tcx - pcx) * (tcx - pcx) + (tcy - pcy) * (tcy - pcy);

    float factor = 4.f / (PIf * PIf);
    float dv = atanf(tw / (th + MEPS)) - atanf(pw / (ph + MEPS));
    float v_ = factor * dv * dv;
    float alpha = (iou > 0.5f) ? v_ / (1.f - iou + v_ + MEPS) : 0.f;

    float rhoterm = fminf(fmaxf(rho2 / c2v, 0.f), 1.f);
    float ciou = iou - (rhoterm + alpha * v_);
    return (1.f - ciou) * wv;
}

__global__ __launch_bounds__(BLOCK)
void obb_ciou_kernel(const float* __restrict__ pred,
                     const float* __restrict__ tgt,
                     const float* __restrict__ wgt,
                     float* __restrict__ out,
                     int N, float invN)
{
    __shared__ float2 slab[BLOCK * LDS_STRIDE];
    float2* myb = slab + (int)threadIdx.x * LDS_STRIDE;

    int blk0 = blockIdx.x * (BLOCK * PAIRS);
    float loss = 0.f;

    // 4 independent pairs per thread, strided so each sub-iteration's wave
    // reads a contiguous region (coalesced). LDS slab reused serially.
    #pragma unroll
    for (int u = 0; u < PAIRS; u++) {
        int i = blk0 + u * BLOCK + (int)threadIdx.x;
        if (i < N)
            loss += pair_loss(pred + (size_t)i * 5, tgt + (size_t)i * 5,
                              wgt[i], myb);
    }

    // ---- reduction: wave shuffle -> LDS -> one atomic per block ----
    #pragma unroll
    for (int off = 32; off > 0; off >>= 1)
        loss += __shfl_down(loss, off, 64);

    __shared__ float red[BLOCK / 64];
    int wave = threadIdx.x >> 6;
    int lane = threadIdx.x & 63;
    if (lane == 0) red[wave] = loss;
    __syncthreads();
    if (threadIdx.x == 0) {
        float s = 0.f;
        #pragma unroll
        for (int w = 0; w < BLOCK / 64; w++) s += red[w];
        atomicAdd(out, s * invN);
    }
}

extern "C" void kernel_launch(void* const* d_in, const int* in_sizes, int n_in,
                              void* d_out, int out_size, void* d_ws, size_t ws_size,
                              hipStream_t stream) {
    const float* pred = (const float*)d_in[0];
    const float* tgt  = (const float*)d_in[1];
    const float* wgt  = (const float*)d_in[2];
    float* out = (float*)d_out;
    int N = in_sizes[2];  // weight element count == N boxes

    hipMemsetAsync(out, 0, sizeof(float) * (size_t)out_size, stream);

    int grid = (N + BLOCK * PAIRS - 1) / (BLOCK * PAIRS);
    obb_ciou_kernel<<<grid, BLOCK, 0, stream>>>(pred, tgt, wgt, out, N,
                                                1.f / (float)N);
}